// Round 3
// baseline (6687.108 us; speedup 1.0000x reference)
//
#include <hip/hip_runtime.h>
#include <hip/hip_cooperative_groups.h>
#include <math.h>

namespace cg = cooperative_groups;

#define BATCH 16
#define IN 128
#define HD 32
#define NN 2048
#define NE 32768
#define SEQ 100
#define NPB 8               // nodes per block
#define GRID (NN / NPB)     // 256 blocks -> 1 per CU, big co-residency margin
#define ECAP 768            // LDS edge cache (avg 128/block; P(>768) ~ 0)
#define BH (BATCH * HD)     // 512

// ---------------- preprocessing ----------------

__global__ void count_deg(const int* __restrict__ src, const int* __restrict__ dst,
                          int* deg_out, int* deg_in) {
    int e = blockIdx.x * blockDim.x + threadIdx.x;
    if (e < NE) {
        atomicAdd(&deg_out[src[e]], 1);
        atomicAdd(&deg_in[dst[e]], 1);
    }
}

__global__ void scan_rowptr(const int* __restrict__ deg_in, int* __restrict__ row_ptr) {
    __shared__ int partial[256];
    int t = threadIdx.x;
    int base = t * 8;
    int vals[8];
    int s = 0;
    for (int j = 0; j < 8; j++) { vals[j] = deg_in[base + j]; s += vals[j]; }
    partial[t] = s;
    __syncthreads();
    if (t == 0) {
        int acc = 0;
        for (int i = 0; i < 256; i++) { int v = partial[i]; partial[i] = acc; acc += v; }
        row_ptr[NN] = acc;
    }
    __syncthreads();
    int acc = partial[t];
    for (int j = 0; j < 8; j++) { row_ptr[base + j] = acc; acc += vals[j]; }
}

__global__ void scatter_edges(const int* __restrict__ src, const int* __restrict__ dst,
                              const int* __restrict__ deg_out, const int* __restrict__ deg_in,
                              const int* __restrict__ row_ptr, int* __restrict__ cursor,
                              int* __restrict__ col_idx, float* __restrict__ wgt) {
    int e = blockIdx.x * blockDim.x + threadIdx.x;
    if (e < NE) {
        int s = src[e], d = dst[e];
        int pos = row_ptr[d] + atomicAdd(&cursor[d], 1);
        col_idx[pos] = s;
        float doo = (float)max(deg_out[s], 1);
        float dii = (float)max(deg_in[d], 1);
        wgt[pos] = rsqrtf(doo * dii);
    }
}

__global__ void xgates(const float* __restrict__ x,
                       const float* __restrict__ Wr, const float* __restrict__ br,
                       const float* __restrict__ Wz, const float* __restrict__ bz,
                       const float* __restrict__ Wh, const float* __restrict__ bh,
                       float* __restrict__ xr, float* __restrict__ xz, float* __restrict__ xh) {
    int t = blockIdx.x * blockDim.x + threadIdx.x;
    if (t < BATCH * HD) {
        int b = t / HD, hh = t % HD;
        float ar = br[hh], az = bz[hh], ah = bh[hh];
        const float* xb = x + b * IN;
        for (int i = 0; i < IN; i++) {
            float xv = xb[i];
            ar += xv * Wr[i * HD + hh];
            az += xv * Wz[i * HD + hh];
            ah += xv * Wh[i * HD + hh];
        }
        xr[t] = ar; xz[t] = az; xh[t] = ah;
    }
}

// ---------------- shared step body ----------------
// h layout: [N][B][H]; thread tid -> (b = tid>>5, l = tid&31)

__device__ __forceinline__ float fast_sigmoid(float x) {
    return __builtin_amdgcn_rcpf(1.f + __expf(-x));
}

__device__ __forceinline__ void step_body(
    int tid, int b, int l, int n0, int t,
    const float* __restrict__ hprev, float* __restrict__ hnext,
    const int* __restrict__ estart, const int* __restrict__ ecol,
    const float* __restrict__ ewgt, const float* __restrict__ wg_s,
    float xrv, float xzv, float xhv, float bgv,
    float* __restrict__ out)
{
    for (int nd = 0; nd < NPB; nd++) {
        const int n = n0 + nd;
        float agg = 0.f;
        const int s = estart[nd], epd = estart[nd + 1];
        for (int e = s; e < epd; e++)
            agg += ewgt[e] * hprev[ecol[e] + tid];

        float conv = bgv;
#pragma unroll
        for (int k = 0; k < HD; k++)
            conv += __shfl(agg, k, 32) * wg_s[k * HD + l];

        const float r = fast_sigmoid(xrv + conv);
        const float z = fast_sigmoid(xzv + conv);
        const float e2 = __expf(2.f * (xhv + r * conv));
        const float ht = 1.f - 2.f * __builtin_amdgcn_rcpf(e2 + 1.f);
        const float hp = hprev[n * BH + tid];
        const float hn = (1.f - z) * hp + z * ht;

        hnext[n * BH + tid] = hn;
        __builtin_nontemporal_store(
            hn, &out[((size_t)b * SEQ + t) * (NN * HD) + (size_t)n * HD + l]);
    }
}

// ---------------- persistent cooperative kernel ----------------

__global__ void __launch_bounds__(512, 2) gru_persistent(
    float* __restrict__ hA, float* __restrict__ hB,
    const int* __restrict__ row_ptr, const int* __restrict__ col_idx,
    const float* __restrict__ wgt,
    const float* __restrict__ Wg, const float* __restrict__ bg,
    const float* __restrict__ xr, const float* __restrict__ xz,
    const float* __restrict__ xh,
    float* __restrict__ out)
{
    __shared__ float wg_s[HD * HD];
    __shared__ int   ecol_s[ECAP];
    __shared__ float ewgt_s[ECAP];
    __shared__ int   estart_s[NPB + 1];

    const int tid = threadIdx.x;
    const int b = tid >> 5;
    const int l = tid & 31;
    const int n0 = blockIdx.x * NPB;

    for (int i = tid; i < HD * HD; i += 512) wg_s[i] = Wg[i];
    if (tid <= NPB) estart_s[tid] = row_ptr[n0 + tid];
    __syncthreads();

    const int e0 = estart_s[0];
    const int ecount = estart_s[NPB] - e0;
    // local (block-relative) starts
    __shared__ int lstart_s[NPB + 1];
    if (tid <= NPB) lstart_s[tid] = estart_s[tid] - e0;
    const bool use_lds = (ecount <= ECAP);
    if (use_lds) {
        for (int i = tid; i < ecount; i += 512) {
            ecol_s[i] = col_idx[e0 + i] * BH;
            ewgt_s[i] = wgt[e0 + i];
        }
    } else {
        // fall back: copy pointers into LDS path unusable; handle rare case below
    }
    __syncthreads();

    const float xrv = xr[b * HD + l];
    const float xzv = xz[b * HD + l];
    const float xhv = xh[b * HD + l];
    const float bgv = bg[l];

    cg::grid_group grid = cg::this_grid();

    const float* hprev = hA;
    float*       hnext = hB;

    for (int t = 0; t < SEQ; t++) {
        if (use_lds) {
            step_body(tid, b, l, n0, t, hprev, hnext,
                      lstart_s, ecol_s, ewgt_s, wg_s, xrv, xzv, xhv, bgv, out);
        } else {
            // rare: stream edges from global
            for (int nd = 0; nd < NPB; nd++) {
                const int n = n0 + nd;
                float agg = 0.f;
                const int s = estart_s[nd], epd = estart_s[nd + 1];
                for (int e = s; e < epd; e++)
                    agg += wgt[e] * hprev[col_idx[e] * BH + tid];
                float conv = bgv;
#pragma unroll
                for (int k = 0; k < HD; k++)
                    conv += __shfl(agg, k, 32) * wg_s[k * HD + l];
                const float r = fast_sigmoid(xrv + conv);
                const float z = fast_sigmoid(xzv + conv);
                const float e2 = __expf(2.f * (xhv + r * conv));
                const float ht = 1.f - 2.f * __builtin_amdgcn_rcpf(e2 + 1.f);
                const float hp = hprev[n * BH + tid];
                const float hn = (1.f - z) * hp + z * ht;
                hnext[n * BH + tid] = hn;
                __builtin_nontemporal_store(
                    hn, &out[((size_t)b * SEQ + t) * (NN * HD) + (size_t)n * HD + l]);
            }
        }
        grid.sync();
        float* tmp = (float*)hprev; hprev = hnext; hnext = tmp;
    }
}

// ---------------- fallback per-step kernel (non-cooperative) ----------------

__global__ void __launch_bounds__(512, 2) step_kernel(
    const float* __restrict__ hprev, float* __restrict__ hnext,
    const int* __restrict__ row_ptr, const int* __restrict__ col_idx,
    const float* __restrict__ wgt,
    const float* __restrict__ Wg, const float* __restrict__ bg,
    const float* __restrict__ xr, const float* __restrict__ xz,
    const float* __restrict__ xh,
    float* __restrict__ out, int t)
{
    __shared__ float wg_s[HD * HD];
    __shared__ int estart_s[NPB + 1];

    const int tid = threadIdx.x;
    const int b = tid >> 5;
    const int l = tid & 31;
    const int n0 = blockIdx.x * NPB;

    for (int i = tid; i < HD * HD; i += 512) wg_s[i] = Wg[i];
    if (tid <= NPB) estart_s[tid] = row_ptr[n0 + tid];
    __syncthreads();

    const float xrv = xr[b * HD + l];
    const float xzv = xz[b * HD + l];
    const float xhv = xh[b * HD + l];
    const float bgv = bg[l];

    for (int nd = 0; nd < NPB; nd++) {
        const int n = n0 + nd;
        float agg = 0.f;
        const int s = estart_s[nd], epd = estart_s[nd + 1];
        for (int e = s; e < epd; e++)
            agg += wgt[e] * hprev[col_idx[e] * BH + tid];
        float conv = bgv;
#pragma unroll
        for (int k = 0; k < HD; k++)
            conv += __shfl(agg, k, 32) * wg_s[k * HD + l];
        const float r = fast_sigmoid(xrv + conv);
        const float z = fast_sigmoid(xzv + conv);
        const float e2 = __expf(2.f * (xhv + r * conv));
        const float ht = 1.f - 2.f * __builtin_amdgcn_rcpf(e2 + 1.f);
        const float hp = hprev[n * BH + tid];
        const float hn = (1.f - z) * hp + z * ht;
        hnext[n * BH + tid] = hn;
        __builtin_nontemporal_store(
            hn, &out[((size_t)b * SEQ + t) * (NN * HD) + (size_t)n * HD + l]);
    }
}

// ---------------- launch ----------------

extern "C" void kernel_launch(void* const* d_in, const int* in_sizes, int n_in,
                              void* d_out, int out_size, void* d_ws, size_t ws_size,
                              hipStream_t stream) {
    const float* x   = (const float*)d_in[0];
    const int*   src = (const int*)d_in[1];
    const int*   dst = (const int*)d_in[2];
    const float* Wr  = (const float*)d_in[3];
    const float* br  = (const float*)d_in[4];
    const float* Wz  = (const float*)d_in[5];
    const float* bz  = (const float*)d_in[6];
    const float* Wh  = (const float*)d_in[7];
    const float* bh  = (const float*)d_in[8];
    const float* Wg  = (const float*)d_in[9];
    const float* bg  = (const float*)d_in[10];
    float* out = (float*)d_out;

    char* ws = (char*)d_ws;
    float* h0 = (float*)ws;            ws += (size_t)BATCH * NN * HD * 4;
    float* h1 = (float*)ws;            ws += (size_t)BATCH * NN * HD * 4;
    float* xr = (float*)ws;            ws += BATCH * HD * 4;
    float* xz = (float*)ws;            ws += BATCH * HD * 4;
    float* xh = (float*)ws;            ws += BATCH * HD * 4;
    int* deg_out = (int*)ws;           ws += NN * 4;
    int* deg_in  = (int*)ws;           ws += NN * 4;
    int* cursor  = (int*)ws;           ws += NN * 4;
    int* row_ptr = (int*)ws;           ws += (NN + 1) * 4;
    int* col_idx = (int*)ws;           ws += NE * 4;
    float* wgt   = (float*)ws;         ws += NE * 4;

    hipMemsetAsync(h0, 0, (size_t)BATCH * NN * HD * 4, stream);
    hipMemsetAsync(deg_out, 0, 3 * NN * 4, stream);

    count_deg<<<NE / 256, 256, 0, stream>>>(src, dst, deg_out, deg_in);
    scan_rowptr<<<1, 256, 0, stream>>>(deg_in, row_ptr);
    scatter_edges<<<NE / 256, 256, 0, stream>>>(src, dst, deg_out, deg_in, row_ptr,
                                                cursor, col_idx, wgt);
    xgates<<<2, 256, 0, stream>>>(x, Wr, br, Wz, bz, Wh, bh, xr, xz, xh);

    void* args[] = { (void*)&h0, (void*)&h1, (void*)&row_ptr, (void*)&col_idx,
                     (void*)&wgt, (void*)&Wg, (void*)&bg, (void*)&xr, (void*)&xz,
                     (void*)&xh, (void*)&out };
    hipError_t err = hipLaunchCooperativeKernel((const void*)gru_persistent,
                                                dim3(GRID), dim3(512), args, 0, stream);
    if (err != hipSuccess) {
        // fallback: 100 sequential launches (kernel boundary = global sync)
        float* hp = h0;
        float* hn = h1;
        for (int t = 0; t < SEQ; t++) {
            step_kernel<<<GRID, 512, 0, stream>>>(hp, hn, row_ptr, col_idx, wgt,
                                                  Wg, bg, xr, xz, xh, out, t);
            float* tmp = hp; hp = hn; hn = tmp;
        }
    }
}

// Round 4
// 4943.326 us; speedup vs baseline: 1.3528x; 1.3528x over previous
//
#include <hip/hip_runtime.h>
#include <hip/hip_cooperative_groups.h>
#include <math.h>

namespace cg = cooperative_groups;

#define BATCH 16
#define IN 128
#define HD 32
#define NN 2048
#define NE 32768
#define SEQ 100
#define BH (BATCH * HD)     // 512
#define WPITCH 34           // padded row pitch for transposed Wg (float2-aligned, conflict-free)

// ---------------- preprocessing ----------------

__global__ void count_deg(const int* __restrict__ src, const int* __restrict__ dst,
                          int* deg_out, int* deg_in) {
    int e = blockIdx.x * blockDim.x + threadIdx.x;
    if (e < NE) {
        atomicAdd(&deg_out[src[e]], 1);
        atomicAdd(&deg_in[dst[e]], 1);
    }
}

__global__ void scan_rowptr(const int* __restrict__ deg_in, int* __restrict__ row_ptr) {
    __shared__ int partial[256];
    int t = threadIdx.x;
    int base = t * 8;
    int vals[8];
    int s = 0;
    for (int j = 0; j < 8; j++) { vals[j] = deg_in[base + j]; s += vals[j]; }
    partial[t] = s;
    __syncthreads();
    if (t == 0) {
        int acc = 0;
        for (int i = 0; i < 256; i++) { int v = partial[i]; partial[i] = acc; acc += v; }
        row_ptr[NN] = acc;
    }
    __syncthreads();
    int acc = partial[t];
    for (int j = 0; j < 8; j++) { row_ptr[base + j] = acc; acc += vals[j]; }
}

__global__ void scatter_edges(const int* __restrict__ src, const int* __restrict__ dst,
                              const int* __restrict__ deg_out, const int* __restrict__ deg_in,
                              const int* __restrict__ row_ptr, int* __restrict__ cursor,
                              int* __restrict__ col_idx, float* __restrict__ wgt) {
    int e = blockIdx.x * blockDim.x + threadIdx.x;
    if (e < NE) {
        int s = src[e], d = dst[e];
        int pos = row_ptr[d] + atomicAdd(&cursor[d], 1);
        col_idx[pos] = s;
        float doo = (float)max(deg_out[s], 1);
        float dii = (float)max(deg_in[d], 1);
        wgt[pos] = rsqrtf(doo * dii);
    }
}

__global__ void xgates(const float* __restrict__ x,
                       const float* __restrict__ Wr, const float* __restrict__ br,
                       const float* __restrict__ Wz, const float* __restrict__ bz,
                       const float* __restrict__ Wh, const float* __restrict__ bh,
                       float* __restrict__ xr, float* __restrict__ xz, float* __restrict__ xh) {
    int t = blockIdx.x * blockDim.x + threadIdx.x;
    if (t < BATCH * HD) {
        int b = t / HD, hh = t % HD;
        float ar = br[hh], az = bz[hh], ah = bh[hh];
        const float* xb = x + b * IN;
        for (int i = 0; i < IN; i++) {
            float xv = xb[i];
            ar += xv * Wr[i * HD + hh];
            az += xv * Wz[i * HD + hh];
            ah += xv * Wh[i * HD + hh];
        }
        xr[t] = ar; xz[t] = az; xh[t] = ah;
    }
}

// ---------------- step body (shared between persistent & fallback) ----------------
// h layout: [N][B][H]; thread tid -> (b = tid>>5, l = tid&31)

__device__ __forceinline__ float fast_sigmoid(float x) {
    return __builtin_amdgcn_rcpf(1.f + __expf(-x));
}

template <int NPB>
__device__ __forceinline__ void gru_step(
    int tid, int b, int l, int n0, int t,
    const float* __restrict__ hprev, float* __restrict__ hnext,
    const int* __restrict__ lstart_s, const int* __restrict__ gstart_s, bool use_lds,
    const int* __restrict__ ecol_s, const float* __restrict__ ewgt_s,
    const int* __restrict__ col_idx, const float* __restrict__ wgt,
    const float* __restrict__ wgT_s, float* __restrict__ aggL,
    float xrv, float xzv, float xhv, float bgv,
    float* __restrict__ out)
{
#pragma unroll
    for (int nd = 0; nd < NPB; nd++) {
        float agg = 0.f;
        if (use_lds) {
            const int s = lstart_s[nd], epd = lstart_s[nd + 1];
            int e = s;
            for (; e + 4 <= epd; e += 4) {
                int c0 = ecol_s[e], c1 = ecol_s[e + 1], c2 = ecol_s[e + 2], c3 = ecol_s[e + 3];
                float w0 = ewgt_s[e], w1 = ewgt_s[e + 1], w2 = ewgt_s[e + 2], w3 = ewgt_s[e + 3];
                float v0 = hprev[c0 + tid];
                float v1 = hprev[c1 + tid];
                float v2 = hprev[c2 + tid];
                float v3 = hprev[c3 + tid];
                agg = fmaf(w0, v0, agg); agg = fmaf(w1, v1, agg);
                agg = fmaf(w2, v2, agg); agg = fmaf(w3, v3, agg);
            }
            for (; e < epd; e++)
                agg = fmaf(ewgt_s[e], hprev[ecol_s[e] + tid], agg);
        } else {
            const int s = gstart_s[nd], epd = gstart_s[nd + 1];
            for (int e = s; e < epd; e++)
                agg = fmaf(wgt[e], hprev[col_idx[e] * BH + tid], agg);
        }

        // matvec: conv[l] = bg[l] + sum_k agg[k] * Wg[k][l]
        // agg broadcast via LDS (wave-lockstep: writer group == reader group, no barrier)
        aggL[tid] = agg;
        const float4* arow = (const float4*)&aggL[tid & ~31];
        const float2* wrow = (const float2*)&wgT_s[l * WPITCH];
        float conv = bgv;
#pragma unroll
        for (int kq = 0; kq < 8; kq++) {
            float4 a4 = arow[kq];
            float2 u0 = wrow[2 * kq], u1 = wrow[2 * kq + 1];
            conv = fmaf(a4.x, u0.x, conv);
            conv = fmaf(a4.y, u0.y, conv);
            conv = fmaf(a4.z, u1.x, conv);
            conv = fmaf(a4.w, u1.y, conv);
        }

        const float r = fast_sigmoid(xrv + conv);
        const float z = fast_sigmoid(xzv + conv);
        const float e2 = __expf(2.f * (xhv + r * conv));
        const float ht = 1.f - 2.f * __builtin_amdgcn_rcpf(e2 + 1.f);
        const int n = n0 + nd;
        const float hp = hprev[n * BH + tid];
        const float hn = (1.f - z) * hp + z * ht;

        hnext[n * BH + tid] = hn;
        __builtin_nontemporal_store(
            hn, &out[((size_t)b * SEQ + t) * (NN * HD) + (size_t)n * HD + l]);
    }
}

// ---------------- persistent cooperative kernel ----------------

template <int NPB>
__global__ void __launch_bounds__(512) gru_persistent(
    float* __restrict__ hA, float* __restrict__ hB,
    const int* __restrict__ row_ptr, const int* __restrict__ col_idx,
    const float* __restrict__ wgt,
    const float* __restrict__ Wg, const float* __restrict__ bg,
    const float* __restrict__ xr, const float* __restrict__ xz,
    const float* __restrict__ xh,
    float* __restrict__ out)
{
    constexpr int ECAP = 128 * NPB;
    __shared__ float wgT_s[HD * WPITCH];
    __shared__ float aggL[512];
    __shared__ int   ecol_s[ECAP];
    __shared__ float ewgt_s[ECAP];
    __shared__ int   gstart_s[NPB + 1];
    __shared__ int   lstart_s[NPB + 1];

    const int tid = threadIdx.x;
    const int b = tid >> 5;
    const int l = tid & 31;
    const int n0 = blockIdx.x * NPB;

    for (int i = tid; i < HD * HD; i += 512) {
        int k = i >> 5, c = i & 31;
        wgT_s[c * WPITCH + k] = Wg[i];
    }
    if (tid <= NPB) gstart_s[tid] = row_ptr[n0 + tid];
    __syncthreads();

    const int e0 = gstart_s[0];
    const int ecount = gstart_s[NPB] - e0;
    if (tid <= NPB) lstart_s[tid] = gstart_s[tid] - e0;
    const bool use_lds = (ecount <= ECAP);
    if (use_lds) {
        for (int i = tid; i < ecount; i += 512) {
            ecol_s[i] = col_idx[e0 + i] * BH;
            ewgt_s[i] = wgt[e0 + i];
        }
    }
    __syncthreads();

    const float xrv = xr[b * HD + l];
    const float xzv = xz[b * HD + l];
    const float xhv = xh[b * HD + l];
    const float bgv = bg[l];

    cg::grid_group grid = cg::this_grid();

    const float* hprev = hA;
    float*       hnext = hB;

    for (int t = 0; t < SEQ; t++) {
        gru_step<NPB>(tid, b, l, n0, t, hprev, hnext, lstart_s, gstart_s, use_lds,
                      ecol_s, ewgt_s, col_idx, wgt, wgT_s, aggL,
                      xrv, xzv, xhv, bgv, out);
        grid.sync();
        float* tmp = (float*)hprev; hprev = hnext; hnext = tmp;
    }
}

// ---------------- fallback per-step kernel (non-cooperative) ----------------

template <int NPB>
__global__ void __launch_bounds__(512) step_fallback(
    const float* __restrict__ hprev, float* __restrict__ hnext,
    const int* __restrict__ row_ptr, const int* __restrict__ col_idx,
    const float* __restrict__ wgt,
    const float* __restrict__ Wg, const float* __restrict__ bg,
    const float* __restrict__ xr, const float* __restrict__ xz,
    const float* __restrict__ xh,
    float* __restrict__ out, int t)
{
    constexpr int ECAP = 128 * NPB;
    __shared__ float wgT_s[HD * WPITCH];
    __shared__ float aggL[512];
    __shared__ int   ecol_s[ECAP];
    __shared__ float ewgt_s[ECAP];
    __shared__ int   gstart_s[NPB + 1];
    __shared__ int   lstart_s[NPB + 1];

    const int tid = threadIdx.x;
    const int b = tid >> 5;
    const int l = tid & 31;
    const int n0 = blockIdx.x * NPB;

    for (int i = tid; i < HD * HD; i += 512) {
        int k = i >> 5, c = i & 31;
        wgT_s[c * WPITCH + k] = Wg[i];
    }
    if (tid <= NPB) gstart_s[tid] = row_ptr[n0 + tid];
    __syncthreads();

    const int e0 = gstart_s[0];
    const int ecount = gstart_s[NPB] - e0;
    if (tid <= NPB) lstart_s[tid] = gstart_s[tid] - e0;
    const bool use_lds = (ecount <= ECAP);
    if (use_lds) {
        for (int i = tid; i < ecount; i += 512) {
            ecol_s[i] = col_idx[e0 + i] * BH;
            ewgt_s[i] = wgt[e0 + i];
        }
    }
    __syncthreads();

    const float xrv = xr[b * HD + l];
    const float xzv = xz[b * HD + l];
    const float xhv = xh[b * HD + l];
    const float bgv = bg[l];

    gru_step<NPB>(tid, b, l, n0, t, hprev, hnext, lstart_s, gstart_s, use_lds,
                  ecol_s, ewgt_s, col_idx, wgt, wgT_s, aggL,
                  xrv, xzv, xhv, bgv, out);
}

// ---------------- launch ----------------

extern "C" void kernel_launch(void* const* d_in, const int* in_sizes, int n_in,
                              void* d_out, int out_size, void* d_ws, size_t ws_size,
                              hipStream_t stream) {
    const float* x   = (const float*)d_in[0];
    const int*   src = (const int*)d_in[1];
    const int*   dst = (const int*)d_in[2];
    const float* Wr  = (const float*)d_in[3];
    const float* br  = (const float*)d_in[4];
    const float* Wz  = (const float*)d_in[5];
    const float* bz  = (const float*)d_in[6];
    const float* Wh  = (const float*)d_in[7];
    const float* bh  = (const float*)d_in[8];
    const float* Wg  = (const float*)d_in[9];
    const float* bg  = (const float*)d_in[10];
    float* out = (float*)d_out;

    char* ws = (char*)d_ws;
    float* h0 = (float*)ws;            ws += (size_t)BATCH * NN * HD * 4;
    float* h1 = (float*)ws;            ws += (size_t)BATCH * NN * HD * 4;
    float* xr = (float*)ws;            ws += BATCH * HD * 4;
    float* xz = (float*)ws;            ws += BATCH * HD * 4;
    float* xh = (float*)ws;            ws += BATCH * HD * 4;
    int* deg_out = (int*)ws;           ws += NN * 4;
    int* deg_in  = (int*)ws;           ws += NN * 4;
    int* cursor  = (int*)ws;           ws += NN * 4;
    int* row_ptr = (int*)ws;           ws += (NN + 1) * 4;
    int* col_idx = (int*)ws;           ws += NE * 4;
    float* wgt   = (float*)ws;         ws += NE * 4;

    hipMemsetAsync(h0, 0, (size_t)BATCH * NN * HD * 4, stream);
    hipMemsetAsync(deg_out, 0, 3 * NN * 4, stream);

    count_deg<<<NE / 256, 256, 0, stream>>>(src, dst, deg_out, deg_in);
    scan_rowptr<<<1, 256, 0, stream>>>(deg_in, row_ptr);
    scatter_edges<<<NE / 256, 256, 0, stream>>>(src, dst, deg_out, deg_in, row_ptr,
                                                cursor, col_idx, wgt);
    xgates<<<2, 256, 0, stream>>>(x, Wr, br, Wz, bz, Wh, bh, xr, xz, xh);

    // capacity-aware cooperative launch (all host-side queries: capture-safe)
    int ncu = 256;
    hipDeviceGetAttribute(&ncu, hipDeviceAttributeMultiprocessorCount, 0);

    int occ2 = 0, occ4 = 0, occ8 = 0;
    if (hipOccupancyMaxActiveBlocksPerMultiprocessor(
            &occ2, (const void*)&gru_persistent<2>, 512, 0) != hipSuccess) occ2 = 0;
    if (hipOccupancyMaxActiveBlocksPerMultiprocessor(
            &occ4, (const void*)&gru_persistent<4>, 512, 0) != hipSuccess) occ4 = 0;
    if (hipOccupancyMaxActiveBlocksPerMultiprocessor(
            &occ8, (const void*)&gru_persistent<8>, 512, 0) != hipSuccess) occ8 = 1;  // round-3-proven config

    void* args[] = { (void*)&h0, (void*)&h1, (void*)&row_ptr, (void*)&col_idx,
                     (void*)&wgt, (void*)&Wg, (void*)&bg, (void*)&xr, (void*)&xz,
                     (void*)&xh, (void*)&out };

    hipError_t err = hipErrorUnknown;
    if ((long)occ2 * ncu >= NN / 2) {
        err = hipLaunchCooperativeKernel((const void*)&gru_persistent<2>,
                                         dim3(NN / 2), dim3(512), args, 0, stream);
    } else if ((long)occ4 * ncu >= NN / 4) {
        err = hipLaunchCooperativeKernel((const void*)&gru_persistent<4>,
                                         dim3(NN / 4), dim3(512), args, 0, stream);
    } else if ((long)occ8 * ncu >= NN / 8) {
        err = hipLaunchCooperativeKernel((const void*)&gru_persistent<8>,
                                         dim3(NN / 8), dim3(512), args, 0, stream);
    }

    if (err != hipSuccess) {
        // fallback: 100 sequential launches (kernel boundary = global sync), NPB=2
        float* hp = h0;
        float* hn = h1;
        for (int t = 0; t < SEQ; t++) {
            step_fallback<2><<<dim3(NN / 2), dim3(512), 0, stream>>>(
                hp, hn, row_ptr, col_idx, wgt, Wg, bg, xr, xz, xh, out, t);
            float* tmp = hp; hp = hn; hn = tmp;
        }
    }
}

// Round 5
// 1161.769 us; speedup vs baseline: 5.7560x; 4.2550x over previous
//
#include <hip/hip_runtime.h>
#include <hip/hip_cooperative_groups.h>
#include <math.h>

#define BATCH 16
#define IN 128
#define HD 32
#define NN 2048
#define NE 32768
#define SEQ 100
#define BH (BATCH * HD)     // 512
#define WPITCH 34           // padded row pitch for transposed Wg (float2-aligned, conflict-free)
#define NPB 2               // nodes per block
#define NBLK (NN / NPB)     // 1024 blocks (proven co-resident in round 4)
#define NGRP 32             // barrier tree fan-in: 32 groups of 32 blocks

// ---------------- preprocessing ----------------

__global__ void count_deg(const int* __restrict__ src, const int* __restrict__ dst,
                          int* deg_out, int* deg_in) {
    int e = blockIdx.x * blockDim.x + threadIdx.x;
    if (e < NE) {
        atomicAdd(&deg_out[src[e]], 1);
        atomicAdd(&deg_in[dst[e]], 1);
    }
}

__global__ void scan_rowptr(const int* __restrict__ deg_in, int* __restrict__ row_ptr) {
    __shared__ int partial[256];
    int t = threadIdx.x;
    int base = t * 8;
    int vals[8];
    int s = 0;
    for (int j = 0; j < 8; j++) { vals[j] = deg_in[base + j]; s += vals[j]; }
    partial[t] = s;
    __syncthreads();
    if (t == 0) {
        int acc = 0;
        for (int i = 0; i < 256; i++) { int v = partial[i]; partial[i] = acc; acc += v; }
        row_ptr[NN] = acc;
    }
    __syncthreads();
    int acc = partial[t];
    for (int j = 0; j < 8; j++) { row_ptr[base + j] = acc; acc += vals[j]; }
}

__global__ void scatter_edges(const int* __restrict__ src, const int* __restrict__ dst,
                              const int* __restrict__ deg_out, const int* __restrict__ deg_in,
                              const int* __restrict__ row_ptr, int* __restrict__ cursor,
                              int* __restrict__ col_idx, float* __restrict__ wgt) {
    int e = blockIdx.x * blockDim.x + threadIdx.x;
    if (e < NE) {
        int s = src[e], d = dst[e];
        int pos = row_ptr[d] + atomicAdd(&cursor[d], 1);
        col_idx[pos] = s;
        float doo = (float)max(deg_out[s], 1);
        float dii = (float)max(deg_in[d], 1);
        wgt[pos] = rsqrtf(doo * dii);
    }
}

__global__ void xgates(const float* __restrict__ x,
                       const float* __restrict__ Wr, const float* __restrict__ br,
                       const float* __restrict__ Wz, const float* __restrict__ bz,
                       const float* __restrict__ Wh, const float* __restrict__ bh,
                       float* __restrict__ xr, float* __restrict__ xz, float* __restrict__ xh) {
    int t = blockIdx.x * blockDim.x + threadIdx.x;
    if (t < BATCH * HD) {
        int b = t / HD, hh = t % HD;
        float ar = br[hh], az = bz[hh], ah = bh[hh];
        const float* xb = x + b * IN;
        for (int i = 0; i < IN; i++) {
            float xv = xb[i];
            ar += xv * Wr[i * HD + hh];
            az += xv * Wz[i * HD + hh];
            ah += xv * Wh[i * HD + hh];
        }
        xr[t] = ar; xz[t] = az; xh[t] = ah;
    }
}

// ---------------- custom grid barrier ----------------
// Two-level tree, monotonic counters (no reset -> no race), s_sleep backoff.
// lvl1: 32 counters, each on its own 128B line. root: 1 counter.
// tgt for step t is 32*(t+1) at BOTH levels (group size 32, 32 leaders).

__device__ __forceinline__ void grid_sync_custom(unsigned* __restrict__ lvl1,
                                                 unsigned* __restrict__ root,
                                                 unsigned tgt) {
    __syncthreads();                       // all block work complete
    if (threadIdx.x == 0) {
        const int gid = blockIdx.x >> 5;
        __builtin_amdgcn_fence(__ATOMIC_RELEASE, "agent");   // drain hnext writes
        __hip_atomic_fetch_add(&lvl1[gid * 32], 1u, __ATOMIC_RELAXED,
                               __HIP_MEMORY_SCOPE_AGENT);
        if ((blockIdx.x & 31) == 0) {
            while (__hip_atomic_load(&lvl1[gid * 32], __ATOMIC_RELAXED,
                                     __HIP_MEMORY_SCOPE_AGENT) < tgt)
                __builtin_amdgcn_s_sleep(2);
            __hip_atomic_fetch_add(root, 1u, __ATOMIC_RELAXED,
                                   __HIP_MEMORY_SCOPE_AGENT);
        }
        while (__hip_atomic_load(root, __ATOMIC_RELAXED,
                                 __HIP_MEMORY_SCOPE_AGENT) < tgt)
            __builtin_amdgcn_s_sleep(2);
        __builtin_amdgcn_fence(__ATOMIC_ACQUIRE, "agent");   // invalidate L1/L2
    }
    __syncthreads();
}

// ---------------- step body ----------------
// h layout: [N][B][H]; thread tid -> (b = tid>>5, l = tid&31)

__device__ __forceinline__ float fast_sigmoid(float x) {
    return __builtin_amdgcn_rcpf(1.f + __expf(-x));
}

template <int NPB_>
__device__ __forceinline__ void gru_step(
    int tid, int b, int l, int n0, int t,
    const float* __restrict__ hprev, float* __restrict__ hnext,
    const int* __restrict__ lstart_s, const int* __restrict__ gstart_s, bool use_lds,
    const int* __restrict__ ecol_s, const float* __restrict__ ewgt_s,
    const int* __restrict__ col_idx, const float* __restrict__ wgt,
    const float* __restrict__ wgT_s, float* __restrict__ aggL,
    float xrv, float xzv, float xhv, float bgv,
    float* __restrict__ out)
{
#pragma unroll
    for (int nd = 0; nd < NPB_; nd++) {
        float agg = 0.f;
        if (use_lds) {
            const int s = lstart_s[nd], epd = lstart_s[nd + 1];
            int e = s;
            for (; e + 4 <= epd; e += 4) {
                int c0 = ecol_s[e], c1 = ecol_s[e + 1], c2 = ecol_s[e + 2], c3 = ecol_s[e + 3];
                float w0 = ewgt_s[e], w1 = ewgt_s[e + 1], w2 = ewgt_s[e + 2], w3 = ewgt_s[e + 3];
                float v0 = hprev[c0 + tid];
                float v1 = hprev[c1 + tid];
                float v2 = hprev[c2 + tid];
                float v3 = hprev[c3 + tid];
                agg = fmaf(w0, v0, agg); agg = fmaf(w1, v1, agg);
                agg = fmaf(w2, v2, agg); agg = fmaf(w3, v3, agg);
            }
            for (; e < epd; e++)
                agg = fmaf(ewgt_s[e], hprev[ecol_s[e] + tid], agg);
        } else {
            const int s = gstart_s[nd], epd = gstart_s[nd + 1];
            for (int e = s; e < epd; e++)
                agg = fmaf(wgt[e], hprev[col_idx[e] * BH + tid], agg);
        }

        // matvec: conv[l] = bg[l] + sum_k agg[k] * Wg[k][l]
        aggL[tid] = agg;
        const float4* arow = (const float4*)&aggL[tid & ~31];
        const float2* wrow = (const float2*)&wgT_s[l * WPITCH];
        float conv = bgv;
#pragma unroll
        for (int kq = 0; kq < 8; kq++) {
            float4 a4 = arow[kq];
            float2 u0 = wrow[2 * kq], u1 = wrow[2 * kq + 1];
            conv = fmaf(a4.x, u0.x, conv);
            conv = fmaf(a4.y, u0.y, conv);
            conv = fmaf(a4.z, u1.x, conv);
            conv = fmaf(a4.w, u1.y, conv);
        }

        const float r = fast_sigmoid(xrv + conv);
        const float z = fast_sigmoid(xzv + conv);
        const float e2 = __expf(2.f * (xhv + r * conv));
        const float ht = 1.f - 2.f * __builtin_amdgcn_rcpf(e2 + 1.f);
        const int n = n0 + nd;
        const float hp = hprev[n * BH + tid];
        const float hn = (1.f - z) * hp + z * ht;

        hnext[n * BH + tid] = hn;
        __builtin_nontemporal_store(
            hn, &out[((size_t)b * SEQ + t) * (NN * HD) + (size_t)n * HD + l]);
    }
}

// ---------------- persistent cooperative kernel (custom barrier) ----------------

__global__ void __launch_bounds__(512) gru_persistent(
    float* __restrict__ hA, float* __restrict__ hB,
    const int* __restrict__ row_ptr, const int* __restrict__ col_idx,
    const float* __restrict__ wgt,
    const float* __restrict__ Wg, const float* __restrict__ bg,
    const float* __restrict__ xr, const float* __restrict__ xz,
    const float* __restrict__ xh,
    float* __restrict__ out,
    unsigned* __restrict__ bar_lvl1, unsigned* __restrict__ bar_root)
{
    constexpr int ECAP = 128 * NPB;
    __shared__ float wgT_s[HD * WPITCH];
    __shared__ float aggL[512];
    __shared__ int   ecol_s[ECAP];
    __shared__ float ewgt_s[ECAP];
    __shared__ int   gstart_s[NPB + 1];
    __shared__ int   lstart_s[NPB + 1];

    const int tid = threadIdx.x;
    const int b = tid >> 5;
    const int l = tid & 31;
    const int n0 = blockIdx.x * NPB;

    for (int i = tid; i < HD * HD; i += 512) {
        int k = i >> 5, c = i & 31;
        wgT_s[c * WPITCH + k] = Wg[i];
    }
    if (tid <= NPB) gstart_s[tid] = row_ptr[n0 + tid];
    __syncthreads();

    const int e0 = gstart_s[0];
    const int ecount = gstart_s[NPB] - e0;
    if (tid <= NPB) lstart_s[tid] = gstart_s[tid] - e0;
    const bool use_lds = (ecount <= ECAP);
    if (use_lds) {
        for (int i = tid; i < ecount; i += 512) {
            ecol_s[i] = col_idx[e0 + i] * BH;
            ewgt_s[i] = wgt[e0 + i];
        }
    }
    __syncthreads();

    const float xrv = xr[b * HD + l];
    const float xzv = xz[b * HD + l];
    const float xhv = xh[b * HD + l];
    const float bgv = bg[l];

    const float* hprev = hA;
    float*       hnext = hB;

    for (int t = 0; t < SEQ; t++) {
        gru_step<NPB>(tid, b, l, n0, t, hprev, hnext, lstart_s, gstart_s, use_lds,
                      ecol_s, ewgt_s, col_idx, wgt, wgT_s, aggL,
                      xrv, xzv, xhv, bgv, out);
        if (t != SEQ - 1)
            grid_sync_custom(bar_lvl1, bar_root, (unsigned)(32 * (t + 1)));
        float* tmp = (float*)hprev; hprev = hnext; hnext = tmp;
    }
}

// ---------------- fallback per-step kernel (non-cooperative) ----------------

__global__ void __launch_bounds__(512) step_fallback(
    const float* __restrict__ hprev, float* __restrict__ hnext,
    const int* __restrict__ row_ptr, const int* __restrict__ col_idx,
    const float* __restrict__ wgt,
    const float* __restrict__ Wg, const float* __restrict__ bg,
    const float* __restrict__ xr, const float* __restrict__ xz,
    const float* __restrict__ xh,
    float* __restrict__ out, int t)
{
    constexpr int ECAP = 128 * NPB;
    __shared__ float wgT_s[HD * WPITCH];
    __shared__ float aggL[512];
    __shared__ int   ecol_s[ECAP];
    __shared__ float ewgt_s[ECAP];
    __shared__ int   gstart_s[NPB + 1];
    __shared__ int   lstart_s[NPB + 1];

    const int tid = threadIdx.x;
    const int b = tid >> 5;
    const int l = tid & 31;
    const int n0 = blockIdx.x * NPB;

    for (int i = tid; i < HD * HD; i += 512) {
        int k = i >> 5, c = i & 31;
        wgT_s[c * WPITCH + k] = Wg[i];
    }
    if (tid <= NPB) gstart_s[tid] = row_ptr[n0 + tid];
    __syncthreads();

    const int e0 = gstart_s[0];
    const int ecount = gstart_s[NPB] - e0;
    if (tid <= NPB) lstart_s[tid] = gstart_s[tid] - e0;
    const bool use_lds = (ecount <= ECAP);
    if (use_lds) {
        for (int i = tid; i < ecount; i += 512) {
            ecol_s[i] = col_idx[e0 + i] * BH;
            ewgt_s[i] = wgt[e0 + i];
        }
    }
    __syncthreads();

    const float xrv = xr[b * HD + l];
    const float xzv = xz[b * HD + l];
    const float xhv = xh[b * HD + l];
    const float bgv = bg[l];

    gru_step<NPB>(tid, b, l, n0, t, hprev, hnext, lstart_s, gstart_s, use_lds,
                  ecol_s, ewgt_s, col_idx, wgt, wgT_s, aggL,
                  xrv, xzv, xhv, bgv, out);
}

// ---------------- launch ----------------

extern "C" void kernel_launch(void* const* d_in, const int* in_sizes, int n_in,
                              void* d_out, int out_size, void* d_ws, size_t ws_size,
                              hipStream_t stream) {
    const float* x   = (const float*)d_in[0];
    const int*   src = (const int*)d_in[1];
    const int*   dst = (const int*)d_in[2];
    const float* Wr  = (const float*)d_in[3];
    const float* br  = (const float*)d_in[4];
    const float* Wz  = (const float*)d_in[5];
    const float* bz  = (const float*)d_in[6];
    const float* Wh  = (const float*)d_in[7];
    const float* bh  = (const float*)d_in[8];
    const float* Wg  = (const float*)d_in[9];
    const float* bg  = (const float*)d_in[10];
    float* out = (float*)d_out;

    char* ws = (char*)d_ws;
    float* h0 = (float*)ws;            ws += (size_t)BATCH * NN * HD * 4;
    float* h1 = (float*)ws;            ws += (size_t)BATCH * NN * HD * 4;
    float* xr = (float*)ws;            ws += BATCH * HD * 4;
    float* xz = (float*)ws;            ws += BATCH * HD * 4;
    float* xh = (float*)ws;            ws += BATCH * HD * 4;
    int* deg_out = (int*)ws;           ws += NN * 4;
    int* deg_in  = (int*)ws;           ws += NN * 4;
    int* cursor  = (int*)ws;           ws += NN * 4;
    int* row_ptr = (int*)ws;           ws += (NN + 1) * 4;
    int* col_idx = (int*)ws;           ws += NE * 4;
    float* wgt   = (float*)ws;         ws += NE * 4;
    // barrier counters: 32 group counters (128B apart) + 1 root, all zeroed per call
    unsigned* bar_lvl1 = (unsigned*)ws; ws += NGRP * 32 * 4;
    unsigned* bar_root = (unsigned*)ws; ws += 32 * 4;

    hipMemsetAsync(h0, 0, (size_t)BATCH * NN * HD * 4, stream);
    hipMemsetAsync(deg_out, 0, 3 * NN * 4, stream);
    hipMemsetAsync(bar_lvl1, 0, (NGRP * 32 + 32) * 4, stream);

    count_deg<<<NE / 256, 256, 0, stream>>>(src, dst, deg_out, deg_in);
    scan_rowptr<<<1, 256, 0, stream>>>(deg_in, row_ptr);
    scatter_edges<<<NE / 256, 256, 0, stream>>>(src, dst, deg_out, deg_in, row_ptr,
                                                cursor, col_idx, wgt);
    xgates<<<2, 256, 0, stream>>>(x, Wr, br, Wz, bz, Wh, bh, xr, xz, xh);

    // capacity check (host-side, capture-safe)
    int ncu = 256;
    hipDeviceGetAttribute(&ncu, hipDeviceAttributeMultiprocessorCount, 0);
    int occ = 0;
    if (hipOccupancyMaxActiveBlocksPerMultiprocessor(
            &occ, (const void*)&gru_persistent, 512, 0) != hipSuccess) occ = 0;

    void* args[] = { (void*)&h0, (void*)&h1, (void*)&row_ptr, (void*)&col_idx,
                     (void*)&wgt, (void*)&Wg, (void*)&bg, (void*)&xr, (void*)&xz,
                     (void*)&xh, (void*)&out, (void*)&bar_lvl1, (void*)&bar_root };

    hipError_t err = hipErrorUnknown;
    if ((long)occ * ncu >= NBLK) {
        err = hipLaunchCooperativeKernel((const void*)&gru_persistent,
                                         dim3(NBLK), dim3(512), args, 0, stream);
    }

    if (err != hipSuccess) {
        // fallback: 100 sequential launches (kernel boundary = global sync)
        float* hp = h0;
        float* hn = h1;
        for (int t = 0; t < SEQ; t++) {
            step_fallback<<<dim3(NBLK), dim3(512), 0, stream>>>(
                hp, hn, row_ptr, col_idx, wgt, Wg, bg, xr, xz, xh, out, t);
            float* tmp = hp; hp = hn; hn = tmp;
        }
    }
}